// Round 15
// baseline (275.252 us; speedup 1.0000x reference)
//
#include <hip/hip_runtime.h>
#include <math.h>

#define SEQ_LEN   720
#define IN_LEN    360
#define PRED_LEN  336
#define CHANNELS  862
#define RANK      32
#define BATCH     256

typedef _Float16 h2 __attribute__((ext_vector_type(2)));

// ws u32/f32 offsets (packed weights only)
#define WS_WH    0        // packed W: u32[360*16]  word[n*16+j] = (W[n][2j], W[n][2j+1])
#define WS_VH    5760     // packed V: u32[336*16]
#define WS_CV    11136    // cvec[336] fp32

// LDS u32 offsets per 256-thr block (14736 u32 = 58944 B; 2 blocks/CU = 117.9 KB)
#define L_A      0        // W u32[5760] during phase 1; V u32[5376] during phase 2
#define L_EX     5760     // 216 slots x 40 u32 (16B-aligned stride) = 8640
#define L_CV     14400    // f32[336]
#define L_TOT    14736

__device__ __forceinline__ float fdot2w(h2 a, h2 b, float c) {
#if __has_builtin(__builtin_amdgcn_fdot2)
    return __builtin_amdgcn_fdot2(a, b, c, false);
#else
    return fmaf((float)a[0], (float)b[0], fmaf((float)a[1], (float)b[1], c));
#endif
}
__device__ __forceinline__ h2 pkrtz(float a, float b) {
    return __builtin_bit_cast(h2, __builtin_amdgcn_cvt_pkrtz(a, b));
}
#define BC(u)  __builtin_bit_cast(h2, (u))
#define BCU(v) __builtin_bit_cast(unsigned, (v))

__device__ __forceinline__ void ntstore8(float* p, float a, float b) {
    float2 v; v.x = a; v.y = b;
    __builtin_nontemporal_store(__builtin_bit_cast(unsigned long long, v),
                                (unsigned long long*)p);
}

// ---------------- fused prep: fold DCT/IDCT and pack fp16 (R13 proven) -------
__global__ __launch_bounds__(256) void k_prep(const float* __restrict__ A,
                                              const float* __restrict__ B,
                                              const float* __restrict__ bias,
                                              unsigned* __restrict__ Wh,
                                              unsigned* __restrict__ Vh,
                                              float* __restrict__ cvec) {
    __shared__ float sbuf[IN_LEN * RANK];
    __shared__ float sres[256];
    const int t = threadIdx.x;
    int blk = blockIdx.x;
    if (blk < 45) {
        for (int i = t; i < IN_LEN * RANK; i += 256) sbuf[i] = A[i];
        __syncthreads();
        int n = blk * 8 + (t >> 5), r = t & 31;
        int step = 2 * n + 1, m = 0;
        float sum = 0.f;
        for (int k = 0; k < IN_LEN; ++k) {
            float coef = (k == 0) ? 0.05270462766947299f
                                  : 0.07453559924999299f;
            float d = coef * cospif((float)m * (1.0f / 720.0f));
            sum = fmaf(d, sbuf[k * RANK + r], sum);
            m += step; if (m >= 1440) m -= 1440;
        }
        sres[t] = sum * 0.0019641855032960957f;
        __syncthreads();
        if (t < 128) {
            int nl = t >> 4, j = t & 15;
            h2 v = pkrtz(sres[nl * 32 + 2 * j], sres[nl * 32 + 2 * j + 1]);
            Wh[(blk * 8 + nl) * 16 + j] = BCU(v);
        }
    } else if (blk < 87) {
        for (int i = t; i < PRED_LEN * RANK; i += 256) {
            int r = i / PRED_LEN, k = i - r * PRED_LEN;
            sbuf[k * RANK + r] = B[i];
        }
        __syncthreads();
        int n = (blk - 45) * 8 + (t >> 5), r = t & 31;
        int step = 2 * n + 1, m = 0;
        float sum = 0.f;
        for (int k = 0; k < PRED_LEN; ++k) {
            float mk = cospif((float)m * (1.0f / 672.0f));
            if (k == 0) mk *= 0.5f;
            sum = fmaf(mk, sbuf[k * RANK + r], sum);
            m += step; if (m >= 1344) m -= 1344;
        }
        sres[t] = sum * (1.0f / 336.0f);
        __syncthreads();
        if (t < 128) {
            int nl = t >> 4, j = t & 15;
            h2 v = pkrtz(sres[nl * 32 + 2 * j], sres[nl * 32 + 2 * j + 1]);
            Vh[((blk - 45) * 8 + nl) * 16 + j] = BCU(v);
        }
    } else {
        int n = (blk - 87) * 256 + t;
        if (n < PRED_LEN) {
            int step = 2 * n + 1, m = 0;
            float sum = 0.f;
            for (int k = 0; k < PRED_LEN; ++k) {
                float mk = cospif((float)m * (1.0f / 672.0f));
                if (k == 0) mk *= 0.5f;
                sum = fmaf(mk, bias[k], sum);
                m += step; if (m >= 1344) m -= 1344;
            }
            cvec[n] = sum * (1.0f / 336.0f);
        }
    }
}

// ---------------- main kernel: 256-thr c-half blocks, 2 independent/CU -------
// grid (2, BATCH): s = c-half (0: ch 0-431, 1: ch 432-861), b = batch.
// Within block: h = tid>>7 k-half groups (108 active of 128, cpt=4),
// R13 recipe: fp16 acc, 4-deep prefetch, fp16 W/V in LDS (V overlays W),
// 2-round LDS exchange, n-split phase 2, nt stores. No inter-block coupling.
__global__ __launch_bounds__(256) void k_main(const float* __restrict__ x,
                                              const float* __restrict__ A,
                                              const unsigned* __restrict__ Wh,
                                              const unsigned* __restrict__ Vh,
                                              const float* __restrict__ cvec,
                                              float* __restrict__ out) {
    __shared__ unsigned ldsu[L_TOT];                 // 58944 B
    const int tid = threadIdx.x;
    const int s = blockIdx.x;
    const int b = blockIdx.y;
    const int h = tid >> 7;
    const int i = tid & 127;
    const bool active = (i < 108);
    int c0 = s * 432 + 4 * i;
    if (c0 > 858) c0 = 858;                          // s=1 tail: dup overlap by 2

    // ---- stage W (region A) + cvec ----
    for (int idx = tid; idx < 1440; idx += 256)
        ((uint4*)(ldsu + L_A))[idx] = ((const uint4*)Wh)[idx];
    for (int idx = tid; idx < 84; idx += 256)
        ((uint4*)(ldsu + L_CV))[idx] = ((const uint4*)cvec)[idx];
    __syncthreads();                                 // B0

    h2 acc0[16], acc1[16], acc2[16], acc3[16];
    #pragma unroll
    for (int j = 0; j < 16; ++j) {
        acc0[j] = pkrtz(0.f, 0.f); acc1[j] = pkrtz(0.f, 0.f);
        acc2[j] = pkrtz(0.f, 0.f); acc3[j] = pkrtz(0.f, 0.f);
    }
    float S0 = 0.f, S1 = 0.f, S2 = 0.f, S3 = 0.f;

    // ---- phase 1: this k-half's 180 n (x rows 360h .. 360h+359) ----
    if (active) {
        const float* xp = x + (size_t)b * (SEQ_LEN * CHANNELS)
                            + (size_t)h * (IN_LEN * CHANNELS) + c0;
        float2 b0[4], b1[4], b2[4], b3[4];
        #define LOADN(BUF, NL) { const float* p_ = xp + (size_t)(2 * (NL)) * CHANNELS; \
            BUF[0] = *(const float2*)(p_);                 \
            BUF[1] = *(const float2*)(p_ + 2);             \
            BUF[2] = *(const float2*)(p_ + CHANNELS);      \
            BUF[3] = *(const float2*)(p_ + CHANNELS + 2); }

        #define BODY(BUF, NL) { \
            float p0 = BUF[0].x + BUF[2].x; \
            float p1 = BUF[0].y + BUF[2].y; \
            float p2 = BUF[1].x + BUF[3].x; \
            float p3 = BUF[1].y + BUF[3].y; \
            S0 += p0; S1 += p1; S2 += p2; S3 += p3; \
            h2 P0 = pkrtz(p0, p0), P1 = pkrtz(p1, p1); \
            h2 P2 = pkrtz(p2, p2), P3 = pkrtz(p3, p3); \
            const uint4* wr = (const uint4*)(ldsu + L_A) + ((NL) + 180 * h) * 4; \
            _Pragma("unroll") \
            for (int q_ = 0; q_ < 4; ++q_) { \
                uint4 wv = wr[q_]; \
                h2 w0 = BC(wv.x), w1 = BC(wv.y), w2 = BC(wv.z), w3 = BC(wv.w); \
                acc0[4*q_+0] = w0 * P0 + acc0[4*q_+0]; \
                acc1[4*q_+0] = w0 * P1 + acc1[4*q_+0]; \
                acc2[4*q_+0] = w0 * P2 + acc2[4*q_+0]; \
                acc3[4*q_+0] = w0 * P3 + acc3[4*q_+0]; \
                acc0[4*q_+1] = w1 * P0 + acc0[4*q_+1]; \
                acc1[4*q_+1] = w1 * P1 + acc1[4*q_+1]; \
                acc2[4*q_+1] = w1 * P2 + acc2[4*q_+1]; \
                acc3[4*q_+1] = w1 * P3 + acc3[4*q_+1]; \
                acc0[4*q_+2] = w2 * P0 + acc0[4*q_+2]; \
                acc1[4*q_+2] = w2 * P1 + acc1[4*q_+2]; \
                acc2[4*q_+2] = w2 * P2 + acc2[4*q_+2]; \
                acc3[4*q_+2] = w2 * P3 + acc3[4*q_+2]; \
                acc0[4*q_+3] = w3 * P0 + acc0[4*q_+3]; \
                acc1[4*q_+3] = w3 * P1 + acc1[4*q_+3]; \
                acc2[4*q_+3] = w3 * P2 + acc2[4*q_+3]; \
                acc3[4*q_+3] = w3 * P3 + acc3[4*q_+3]; \
            } }

        #define CL(nn) ((nn) < 180 ? (nn) : 179)
        LOADN(b0, 0) LOADN(b1, 1) LOADN(b2, 2)
        for (int it = 0; it < 45; ++it) {
            const int base = 4 * it;
            LOADN(b3, base + 3)      BODY(b0, base)
            LOADN(b0, CL(base + 4))  BODY(b1, base + 1)
            LOADN(b1, CL(base + 5))  BODY(b2, base + 2)
            LOADN(b2, CL(base + 6))  BODY(b3, base + 3)
        }
        #undef CL
        #undef BODY
        #undef LOADN
    }
    __syncthreads();                                 // B1: W reads done

    // ---- stage V over region A (W dead) + exchange round 1 (ch 0,1) ----
    for (int idx = tid; idx < 1344; idx += 256)
        ((uint4*)(ldsu + L_A))[idx] = ((const uint4*)Vh)[idx];
    if (active) {
        unsigned* rec = ldsu + L_EX + (i + 108 * h) * 40;
        #pragma unroll
        for (int q = 0; q < 4; ++q) {
            uint4 v;
            v.x = BCU(acc0[4*q+0]); v.y = BCU(acc0[4*q+1]);
            v.z = BCU(acc0[4*q+2]); v.w = BCU(acc0[4*q+3]);
            ((uint4*)rec)[q] = v;
            v.x = BCU(acc1[4*q+0]); v.y = BCU(acc1[4*q+1]);
            v.z = BCU(acc1[4*q+2]); v.w = BCU(acc1[4*q+3]);
            ((uint4*)rec)[4 + q] = v;
        }
        rec[32] = __float_as_uint(S0);
        rec[33] = __float_as_uint(S1);
    }
    __syncthreads();                                 // B2
    if (active) {
        const unsigned* pr = ldsu + L_EX + (i + 108 * (1 - h)) * 40;
        #pragma unroll
        for (int q = 0; q < 4; ++q) {
            uint4 v = ((const uint4*)pr)[q];
            acc0[4*q+0] = acc0[4*q+0] + BC(v.x); acc0[4*q+1] = acc0[4*q+1] + BC(v.y);
            acc0[4*q+2] = acc0[4*q+2] + BC(v.z); acc0[4*q+3] = acc0[4*q+3] + BC(v.w);
            v = ((const uint4*)pr)[4 + q];
            acc1[4*q+0] = acc1[4*q+0] + BC(v.x); acc1[4*q+1] = acc1[4*q+1] + BC(v.y);
            acc1[4*q+2] = acc1[4*q+2] + BC(v.z); acc1[4*q+3] = acc1[4*q+3] + BC(v.w);
        }
        S0 += __uint_as_float(pr[32]);
        S1 += __uint_as_float(pr[33]);
    }
    __syncthreads();                                 // B3: round-1 reads done

    // ---- exchange round 2 (ch 2,3) ----
    if (active) {
        unsigned* rec = ldsu + L_EX + (i + 108 * h) * 40;
        #pragma unroll
        for (int q = 0; q < 4; ++q) {
            uint4 v;
            v.x = BCU(acc2[4*q+0]); v.y = BCU(acc2[4*q+1]);
            v.z = BCU(acc2[4*q+2]); v.w = BCU(acc2[4*q+3]);
            ((uint4*)rec)[q] = v;
            v.x = BCU(acc3[4*q+0]); v.y = BCU(acc3[4*q+1]);
            v.z = BCU(acc3[4*q+2]); v.w = BCU(acc3[4*q+3]);
            ((uint4*)rec)[4 + q] = v;
        }
        rec[32] = __float_as_uint(S2);
        rec[33] = __float_as_uint(S3);
    }
    __syncthreads();                                 // B4
    if (active) {
        const unsigned* pr = ldsu + L_EX + (i + 108 * (1 - h)) * 40;
        #pragma unroll
        for (int q = 0; q < 4; ++q) {
            uint4 v = ((const uint4*)pr)[q];
            acc2[4*q+0] = acc2[4*q+0] + BC(v.x); acc2[4*q+1] = acc2[4*q+1] + BC(v.y);
            acc2[4*q+2] = acc2[4*q+2] + BC(v.z); acc2[4*q+3] = acc2[4*q+3] + BC(v.w);
            v = ((const uint4*)pr)[4 + q];
            acc3[4*q+0] = acc3[4*q+0] + BC(v.x); acc3[4*q+1] = acc3[4*q+1] + BC(v.y);
            acc3[4*q+2] = acc3[4*q+2] + BC(v.z); acc3[4*q+3] = acc3[4*q+3] + BC(v.w);
        }
        S2 += __uint_as_float(pr[32]);
        S3 += __uint_as_float(pr[33]);

        // ---- finalize: t[r] -= S*(1/360)*A[0][r]/sqrt(720) ----
        const float kc = (1.0f / 360.0f) * 0.037267799624996496f;
        float g0 = -S0 * kc, g1 = -S1 * kc, g2 = -S2 * kc, g3 = -S3 * kc;
        h2 G0 = pkrtz(g0, g0), G1 = pkrtz(g1, g1), G2 = pkrtz(g2, g2), G3 = pkrtz(g3, g3);
        #pragma unroll
        for (int q = 0; q < 8; ++q) {
            float4 a4 = ((const float4*)A)[q];       // A[0][0..31], uniform, L2-hot
            h2 aa = pkrtz(a4.x, a4.y), ab = pkrtz(a4.z, a4.w);
            acc0[2*q]   = aa * G0 + acc0[2*q];   acc0[2*q+1] = ab * G0 + acc0[2*q+1];
            acc1[2*q]   = aa * G1 + acc1[2*q];   acc1[2*q+1] = ab * G1 + acc1[2*q+1];
            acc2[2*q]   = aa * G2 + acc2[2*q];   acc2[2*q+1] = ab * G2 + acc2[2*q+1];
            acc3[2*q]   = aa * G3 + acc3[2*q];   acc3[2*q+1] = ab * G3 + acc3[2*q+1];
        }
        const float mean0 = S0 * (1.0f / 720.0f), mean1 = S1 * (1.0f / 720.0f);
        const float mean2 = S2 * (1.0f / 720.0f), mean3 = S3 * (1.0f / 720.0f);

        // ---- phase 2: this group's 168 output rows (nt stores) ----
        float* op = out + (size_t)b * (PRED_LEN * CHANNELS)
                        + (size_t)(168 * h) * CHANNELS + c0;
        for (int nl = 0; nl < 168; ++nl) {
            const int n = 168 * h + nl;
            const uint4* vr = (const uint4*)(ldsu + L_A) + n * 4;
            float o0 = 0.f, o1 = 0.f, o2 = 0.f, o3 = 0.f;
            float e0 = 0.f, e1 = 0.f, e2 = 0.f, e3 = 0.f;
            #pragma unroll
            for (int q = 0; q < 4; ++q) {
                uint4 v = vr[q];
                h2 v0 = BC(v.x), v1 = BC(v.y), v2 = BC(v.z), v3 = BC(v.w);
                o0 = fdot2w(acc0[4*q+0], v0, o0); e0 = fdot2w(acc0[4*q+1], v1, e0);
                o1 = fdot2w(acc1[4*q+0], v0, o1); e1 = fdot2w(acc1[4*q+1], v1, e1);
                o2 = fdot2w(acc2[4*q+0], v0, o2); e2 = fdot2w(acc2[4*q+1], v1, e2);
                o3 = fdot2w(acc3[4*q+0], v0, o3); e3 = fdot2w(acc3[4*q+1], v1, e3);
                o0 = fdot2w(acc0[4*q+2], v2, o0); e0 = fdot2w(acc0[4*q+3], v3, e0);
                o1 = fdot2w(acc1[4*q+2], v2, o1); e1 = fdot2w(acc1[4*q+3], v3, e1);
                o2 = fdot2w(acc2[4*q+2], v2, o2); e2 = fdot2w(acc2[4*q+3], v3, e2);
                o3 = fdot2w(acc3[4*q+2], v2, o3); e3 = fdot2w(acc3[4*q+3], v3, e3);
            }
            float cvn = ((const float*)(ldsu + L_CV))[n];
            ntstore8(op,     (o0 + e0) + cvn + mean0, (o1 + e1) + cvn + mean1);
            ntstore8(op + 2, (o2 + e2) + cvn + mean2, (o3 + e3) + cvn + mean3);
            op += CHANNELS;
        }
    }
}

// ---------------- launcher ---------------------------------------------------

extern "C" void kernel_launch(void* const* d_in, const int* in_sizes, int n_in,
                              void* d_out, int out_size, void* d_ws, size_t ws_size,
                              hipStream_t stream) {
    (void)in_sizes; (void)n_in; (void)out_size; (void)ws_size;
    const float* x    = (const float*)d_in[0];
    const float* A    = (const float*)d_in[1];
    const float* B    = (const float*)d_in[2];
    const float* bias = (const float*)d_in[3];
    float* out = (float*)d_out;

    unsigned* Wh   = (unsigned*)d_ws + WS_WH;
    unsigned* Vh   = (unsigned*)d_ws + WS_VH;
    float*    cvec = (float*)d_ws + WS_CV;

    k_prep<<<dim3(89), dim3(256), 0, stream>>>(A, B, bias, Wh, Vh, cvec);
    k_main<<<dim3(2, BATCH), dim3(256), 0, stream>>>(x, A, Wh, Vh, cvec, out);
}

// Round 16
// 248.640 us; speedup vs baseline: 1.1070x; 1.1070x over previous
//
#include <hip/hip_runtime.h>
#include <math.h>

#define SEQ_LEN   720
#define IN_LEN    360
#define PRED_LEN  336
#define CHANNELS  862
#define RANK      32
#define BATCH     256

typedef _Float16 h2 __attribute__((ext_vector_type(2)));
typedef float    f4 __attribute__((ext_vector_type(4)));
typedef float    f4a __attribute__((ext_vector_type(4), aligned(4)));  // misaligned-capable

// ws u32/f32 offsets (packed weights only)
#define WS_WH    0        // packed W: u32[360*16]  word[n*16+j] = (W[n][2j], W[n][2j+1])
#define WS_VH    5760     // packed V: u32[336*16]
#define WS_CV    11136    // cvec[336] fp32

// LDS u32 offsets (total 40848 u32 = 163392 B; proven OK R10/R13)
#define L_EX     0        // [432 slots][68 u32]
#define L_W      29376    // u32[5760]
#define L_V      35136    // u32[5376]
#define L_CV     40512    // f32[336]

__device__ __forceinline__ float fdot2w(h2 a, h2 b, float c) {
#if __has_builtin(__builtin_amdgcn_fdot2)
    return __builtin_amdgcn_fdot2(a, b, c, false);
#else
    return fmaf((float)a[0], (float)b[0], fmaf((float)a[1], (float)b[1], c));
#endif
}
__device__ __forceinline__ h2 pkrtz(float a, float b) {
    return __builtin_bit_cast(h2, __builtin_amdgcn_cvt_pkrtz(a, b));
}
#define BC(u)  __builtin_bit_cast(h2, (u))
#define BCU(v) __builtin_bit_cast(unsigned, (v))

__device__ __forceinline__ void ntstore16(float* p, f4 v) {
    __builtin_nontemporal_store(v, (f4a*)p);        // 16B store, 4B-align OK
}

// ---------------- fused prep: fold DCT/IDCT and pack fp16 (R13 proven) -------
__global__ __launch_bounds__(256) void k_prep(const float* __restrict__ A,
                                              const float* __restrict__ B,
                                              const float* __restrict__ bias,
                                              unsigned* __restrict__ Wh,
                                              unsigned* __restrict__ Vh,
                                              float* __restrict__ cvec) {
    __shared__ float sbuf[IN_LEN * RANK];
    __shared__ float sres[256];
    const int t = threadIdx.x;
    int blk = blockIdx.x;
    if (blk < 45) {
        for (int i = t; i < IN_LEN * RANK; i += 256) sbuf[i] = A[i];
        __syncthreads();
        int n = blk * 8 + (t >> 5), r = t & 31;
        int step = 2 * n + 1, m = 0;
        float sum = 0.f;
        for (int k = 0; k < IN_LEN; ++k) {
            float coef = (k == 0) ? 0.05270462766947299f
                                  : 0.07453559924999299f;
            float d = coef * cospif((float)m * (1.0f / 720.0f));
            sum = fmaf(d, sbuf[k * RANK + r], sum);
            m += step; if (m >= 1440) m -= 1440;
        }
        sres[t] = sum * 0.0019641855032960957f;
        __syncthreads();
        if (t < 128) {
            int nl = t >> 4, j = t & 15;
            h2 v = pkrtz(sres[nl * 32 + 2 * j], sres[nl * 32 + 2 * j + 1]);
            Wh[(blk * 8 + nl) * 16 + j] = BCU(v);
        }
    } else if (blk < 87) {
        for (int i = t; i < PRED_LEN * RANK; i += 256) {
            int r = i / PRED_LEN, k = i - r * PRED_LEN;
            sbuf[k * RANK + r] = B[i];
        }
        __syncthreads();
        int n = (blk - 45) * 8 + (t >> 5), r = t & 31;
        int step = 2 * n + 1, m = 0;
        float sum = 0.f;
        for (int k = 0; k < PRED_LEN; ++k) {
            float mk = cospif((float)m * (1.0f / 672.0f));
            if (k == 0) mk *= 0.5f;
            sum = fmaf(mk, sbuf[k * RANK + r], sum);
            m += step; if (m >= 1344) m -= 1344;
        }
        sres[t] = sum * (1.0f / 336.0f);
        __syncthreads();
        if (t < 128) {
            int nl = t >> 4, j = t & 15;
            h2 v = pkrtz(sres[nl * 32 + 2 * j], sres[nl * 32 + 2 * j + 1]);
            Vh[((blk - 45) * 8 + nl) * 16 + j] = BCU(v);
        }
    } else {
        int n = (blk - 87) * 256 + t;
        if (n < PRED_LEN) {
            int step = 2 * n + 1, m = 0;
            float sum = 0.f;
            for (int k = 0; k < PRED_LEN; ++k) {
                float mk = cospif((float)m * (1.0f / 672.0f));
                if (k == 0) mk *= 0.5f;
                sum = fmaf(mk, bias[k], sum);
                m += step; if (m >= 1344) m -= 1344;
            }
            cvec[n] = sum * (1.0f / 336.0f);
        }
    }
}

// ---------------- fused main kernel (R13 + all-16B vmem) ---------------------
// One 512-thr block per batch. tid>>8 = K-half; i<216 active, 4 ch/thread.
// ALL global accesses are single dwordx4 instructions (odd rows via align(4)
// vector type -> HW misaligned 16B access). Per-thread vmem: 360 loads + 168
// nt stores (was 876). fp16 packed acc; LDS exchange; n-split phase 2.
__global__ __launch_bounds__(512) void k_main(const float* __restrict__ x,
                                              const float* __restrict__ A,
                                              const unsigned* __restrict__ Wh,
                                              const unsigned* __restrict__ Vh,
                                              const float* __restrict__ cvec,
                                              float* __restrict__ out) {
    __shared__ unsigned ldsu[40848];
    const int tid = threadIdx.x;
    const int b = blockIdx.x;
    const int h = tid >> 8;
    const int i = tid & 255;
    const bool active = (i < 216);
    const int c0 = (i < 215) ? 4 * i : 858;

    for (int idx = tid; idx < 1440; idx += 512)
        ((uint4*)(ldsu + L_W))[idx] = ((const uint4*)Wh)[idx];
    for (int idx = tid; idx < 1344; idx += 512)
        ((uint4*)(ldsu + L_V))[idx] = ((const uint4*)Vh)[idx];
    for (int idx = tid; idx < 84; idx += 512)
        ((uint4*)(ldsu + L_CV))[idx] = ((const uint4*)cvec)[idx];
    __syncthreads();

    h2 acc0[16], acc1[16], acc2[16], acc3[16];
    #pragma unroll
    for (int j = 0; j < 16; ++j) {
        acc0[j] = pkrtz(0.f, 0.f); acc1[j] = pkrtz(0.f, 0.f);
        acc2[j] = pkrtz(0.f, 0.f); acc3[j] = pkrtz(0.f, 0.f);
    }
    float S0 = 0.f, S1 = 0.f, S2 = 0.f, S3 = 0.f;

    if (active) {
        const float* xp = x + (size_t)b * (SEQ_LEN * CHANNELS)
                            + (size_t)h * (IN_LEN * CHANNELS) + c0;
        f4 e0_, o0_, e1_, o1_, e2_, o2_, e3_, o3_;

        #define LOADN(K, NL) { const float* p_ = xp + (size_t)(2 * (NL)) * CHANNELS; \
            e##K##_ = *(const f4a*)(p_);             \
            o##K##_ = *(const f4a*)(p_ + CHANNELS); }

        #define BODY(K, NL) { \
            float p0 = e##K##_.x + o##K##_.x; \
            float p1 = e##K##_.y + o##K##_.y; \
            float p2 = e##K##_.z + o##K##_.z; \
            float p3 = e##K##_.w + o##K##_.w; \
            S0 += p0; S1 += p1; S2 += p2; S3 += p3; \
            h2 P0 = pkrtz(p0, p0), P1 = pkrtz(p1, p1); \
            h2 P2 = pkrtz(p2, p2), P3 = pkrtz(p3, p3); \
            const uint4* wr = (const uint4*)(ldsu + L_W) + ((NL) + 180 * h) * 4; \
            _Pragma("unroll") \
            for (int q_ = 0; q_ < 4; ++q_) { \
                uint4 wv = wr[q_]; \
                h2 w0 = BC(wv.x), w1 = BC(wv.y), w2 = BC(wv.z), w3 = BC(wv.w); \
                acc0[4*q_+0] = w0 * P0 + acc0[4*q_+0]; \
                acc1[4*q_+0] = w0 * P1 + acc1[4*q_+0]; \
                acc2[4*q_+0] = w0 * P2 + acc2[4*q_+0]; \
                acc3[4*q_+0] = w0 * P3 + acc3[4*q_+0]; \
                acc0[4*q_+1] = w1 * P0 + acc0[4*q_+1]; \
                acc1[4*q_+1] = w1 * P1 + acc1[4*q_+1]; \
                acc2[4*q_+1] = w1 * P2 + acc2[4*q_+1]; \
                acc3[4*q_+1] = w1 * P3 + acc3[4*q_+1]; \
                acc0[4*q_+2] = w2 * P0 + acc0[4*q_+2]; \
                acc1[4*q_+2] = w2 * P1 + acc1[4*q_+2]; \
                acc2[4*q_+2] = w2 * P2 + acc2[4*q_+2]; \
                acc3[4*q_+2] = w2 * P3 + acc3[4*q_+2]; \
                acc0[4*q_+3] = w3 * P0 + acc0[4*q_+3]; \
                acc1[4*q_+3] = w3 * P1 + acc1[4*q_+3]; \
                acc2[4*q_+3] = w3 * P2 + acc2[4*q_+3]; \
                acc3[4*q_+3] = w3 * P3 + acc3[4*q_+3]; \
            } }

        #define CL(nn) ((nn) < 180 ? (nn) : 179)
        LOADN(0, 0) LOADN(1, 1) LOADN(2, 2)
        for (int it = 0; it < 45; ++it) {            // 4 n per iter
            const int base = 4 * it;
            LOADN(3, base + 3)      BODY(0, base)
            LOADN(0, CL(base + 4))  BODY(1, base + 1)
            LOADN(1, CL(base + 5))  BODY(2, base + 2)
            LOADN(2, CL(base + 6))  BODY(3, base + 3)
        }
        #undef CL
        #undef BODY
        #undef LOADN
    }

    // ---- write partial record (16B-aligned: 272 B/slot) ----
    if (active) {
        uint4* rec = (uint4*)(ldsu + (i + 216 * h) * 68);
        #pragma unroll
        for (int q = 0; q < 4; ++q) {
            uint4 v;
            v.x = BCU(acc0[4*q+0]); v.y = BCU(acc0[4*q+1]);
            v.z = BCU(acc0[4*q+2]); v.w = BCU(acc0[4*q+3]);
            rec[q] = v;
            v.x = BCU(acc1[4*q+0]); v.y = BCU(acc1[4*q+1]);
            v.z = BCU(acc1[4*q+2]); v.w = BCU(acc1[4*q+3]);
            rec[4 + q] = v;
            v.x = BCU(acc2[4*q+0]); v.y = BCU(acc2[4*q+1]);
            v.z = BCU(acc2[4*q+2]); v.w = BCU(acc2[4*q+3]);
            rec[8 + q] = v;
            v.x = BCU(acc3[4*q+0]); v.y = BCU(acc3[4*q+1]);
            v.z = BCU(acc3[4*q+2]); v.w = BCU(acc3[4*q+3]);
            rec[12 + q] = v;
        }
        uint4 sv;
        sv.x = __float_as_uint(S0); sv.y = __float_as_uint(S1);
        sv.z = __float_as_uint(S2); sv.w = __float_as_uint(S3);
        rec[16] = sv;
    }
    __syncthreads();

    if (active) {
        const uint4* pr = (const uint4*)(ldsu + (i + 216 * (1 - h)) * 68);
        #pragma unroll
        for (int q = 0; q < 4; ++q) {
            uint4 v = pr[q];
            acc0[4*q+0] = acc0[4*q+0] + BC(v.x); acc0[4*q+1] = acc0[4*q+1] + BC(v.y);
            acc0[4*q+2] = acc0[4*q+2] + BC(v.z); acc0[4*q+3] = acc0[4*q+3] + BC(v.w);
            v = pr[4 + q];
            acc1[4*q+0] = acc1[4*q+0] + BC(v.x); acc1[4*q+1] = acc1[4*q+1] + BC(v.y);
            acc1[4*q+2] = acc1[4*q+2] + BC(v.z); acc1[4*q+3] = acc1[4*q+3] + BC(v.w);
            v = pr[8 + q];
            acc2[4*q+0] = acc2[4*q+0] + BC(v.x); acc2[4*q+1] = acc2[4*q+1] + BC(v.y);
            acc2[4*q+2] = acc2[4*q+2] + BC(v.z); acc2[4*q+3] = acc2[4*q+3] + BC(v.w);
            v = pr[12 + q];
            acc3[4*q+0] = acc3[4*q+0] + BC(v.x); acc3[4*q+1] = acc3[4*q+1] + BC(v.y);
            acc3[4*q+2] = acc3[4*q+2] + BC(v.z); acc3[4*q+3] = acc3[4*q+3] + BC(v.w);
        }
        uint4 sv = pr[16];
        float S0f = S0 + __uint_as_float(sv.x), S1f = S1 + __uint_as_float(sv.y);
        float S2f = S2 + __uint_as_float(sv.z), S3f = S3 + __uint_as_float(sv.w);

        const float kc = (1.0f / 360.0f) * 0.037267799624996496f;
        float g0 = -S0f * kc, g1 = -S1f * kc, g2 = -S2f * kc, g3 = -S3f * kc;
        h2 G0 = pkrtz(g0, g0), G1 = pkrtz(g1, g1), G2 = pkrtz(g2, g2), G3 = pkrtz(g3, g3);
        #pragma unroll
        for (int q = 0; q < 8; ++q) {
            float4 a4 = ((const float4*)A)[q];       // A[0][0..31], uniform, L2-hot
            h2 aa = pkrtz(a4.x, a4.y), ab = pkrtz(a4.z, a4.w);
            acc0[2*q]   = aa * G0 + acc0[2*q];   acc0[2*q+1] = ab * G0 + acc0[2*q+1];
            acc1[2*q]   = aa * G1 + acc1[2*q];   acc1[2*q+1] = ab * G1 + acc1[2*q+1];
            acc2[2*q]   = aa * G2 + acc2[2*q];   acc2[2*q+1] = ab * G2 + acc2[2*q+1];
            acc3[2*q]   = aa * G3 + acc3[2*q];   acc3[2*q+1] = ab * G3 + acc3[2*q+1];
        }
        const float mean0 = S0f * (1.0f / 720.0f), mean1 = S1f * (1.0f / 720.0f);
        const float mean2 = S2f * (1.0f / 720.0f), mean3 = S3f * (1.0f / 720.0f);

        // ---- phase 2: 168 rows, ONE 16B nt store per row ----
        float* op = out + (size_t)b * (PRED_LEN * CHANNELS)
                        + (size_t)(168 * h) * CHANNELS + c0;
        for (int nl = 0; nl < 168; ++nl) {
            const int n = 168 * h + nl;
            const uint4* vr = (const uint4*)(ldsu + L_V) + n * 4;
            float o0 = 0.f, o1 = 0.f, o2 = 0.f, o3 = 0.f;
            float e0 = 0.f, e1 = 0.f, e2 = 0.f, e3 = 0.f;
            #pragma unroll
            for (int q = 0; q < 4; ++q) {
                uint4 v = vr[q];
                h2 v0 = BC(v.x), v1 = BC(v.y), v2 = BC(v.z), v3 = BC(v.w);
                o0 = fdot2w(acc0[4*q+0], v0, o0); e0 = fdot2w(acc0[4*q+1], v1, e0);
                o1 = fdot2w(acc1[4*q+0], v0, o1); e1 = fdot2w(acc1[4*q+1], v1, e1);
                o2 = fdot2w(acc2[4*q+0], v0, o2); e2 = fdot2w(acc2[4*q+1], v1, e2);
                o3 = fdot2w(acc3[4*q+0], v0, o3); e3 = fdot2w(acc3[4*q+1], v1, e3);
                o0 = fdot2w(acc0[4*q+2], v2, o0); e0 = fdot2w(acc0[4*q+3], v3, e0);
                o1 = fdot2w(acc1[4*q+2], v2, o1); e1 = fdot2w(acc1[4*q+3], v3, e1);
                o2 = fdot2w(acc2[4*q+2], v2, o2); e2 = fdot2w(acc2[4*q+3], v3, e2);
                o3 = fdot2w(acc3[4*q+2], v2, o3); e3 = fdot2w(acc3[4*q+3], v3, e3);
            }
            float cvn = ((const float*)(ldsu + L_CV))[n];
            f4 w;
            w.x = (o0 + e0) + cvn + mean0;
            w.y = (o1 + e1) + cvn + mean1;
            w.z = (o2 + e2) + cvn + mean2;
            w.w = (o3 + e3) + cvn + mean3;
            ntstore16(op, w);
            op += CHANNELS;
        }
    }
}

// ---------------- launcher ---------------------------------------------------

extern "C" void kernel_launch(void* const* d_in, const int* in_sizes, int n_in,
                              void* d_out, int out_size, void* d_ws, size_t ws_size,
                              hipStream_t stream) {
    (void)in_sizes; (void)n_in; (void)out_size; (void)ws_size;
    const float* x    = (const float*)d_in[0];
    const float* A    = (const float*)d_in[1];
    const float* B    = (const float*)d_in[2];
    const float* bias = (const float*)d_in[3];
    float* out = (float*)d_out;

    unsigned* Wh   = (unsigned*)d_ws + WS_WH;
    unsigned* Vh   = (unsigned*)d_ws + WS_VH;
    float*    cvec = (float*)d_ws + WS_CV;

    k_prep<<<dim3(89), dim3(256), 0, stream>>>(A, B, bias, Wh, Vh, cvec);
    k_main<<<dim3(BATCH), dim3(512), 0, stream>>>(x, A, Wh, Vh, cvec, out);
}